// Round 13
// baseline (40.443 us; speedup 1.0000x reference)
//
#include <hip/hip_runtime.h>

typedef float v2f __attribute__((ext_vector_type(2)));
typedef _Float16 h8 __attribute__((ext_vector_type(8)));

constexpr int B = 4, H = 8, N = 256, D = 64;
constexpr int QBLK = 4;
constexpr int PATTN_OFF = B * H * N * D;   // 524288
constexpr int NROWS = B * H * N;           // 8192

// ws layout (floats): qp[NROWS*64] | kpb[NROWS*64] | cq6[NROWS] | ck6[NROWS] | w4[64]

// proj: unchanged from R12 (grid 512, 4 rows/wave, 2 blocks/CU, LDS-transposed
// W_h stride 65 conflict-free).
__global__ __launch_bounds__(256, 2) void proj_kernel(
    const float* __restrict__ q, const float* __restrict__ k,
    const float* __restrict__ W_h, const float* __restrict__ b_h,
    const float* __restrict__ W_o, const float* __restrict__ b_o,
    float* __restrict__ qp, float* __restrict__ kpb,
    float* __restrict__ cq6, float* __restrict__ ck6, float* __restrict__ w4)
{
    __shared__ float WT[128 * 65];
    int t = threadIdx.x;
    int lane = t & 63;
    int wid = __builtin_amdgcn_readfirstlane(t >> 6);
    int bid = blockIdx.x;
    int work = (bid & 7) * 64 + (bid >> 3);   // 512 = 8*64 bijective XCD swizzle

    #pragma unroll
    for (int i = 0; i < 8; ++i) {
        int fidx = (t + i * 256) * 4;
        float4 w = *reinterpret_cast<const float4*>(W_h + fidx);
        int e = fidx >> 7, d = fidx & 127;
        WT[(d + 0) * 65 + e] = w.x;
        WT[(d + 1) * 65 + e] = w.y;
        WT[(d + 2) * 65 + e] = w.z;
        WT[(d + 3) * 65 + e] = w.w;
    }
    if (bid == 0 && t < 64) w4[t] = 0.4f * W_o[t];
    __syncthreads();

    int rbase = work * 16 + wid * 4;   // 4 rows per wave, e = lane
    float accq[4] = {}, acck[4] = {};
    #pragma unroll
    for (int d0 = 0; d0 < 64; d0 += 16) {
        float wq[16], wk[16];
        #pragma unroll
        for (int d = 0; d < 16; ++d) {
            wq[d] = WT[(d0 + d) * 65 + lane];
            wk[d] = WT[(64 + d0 + d) * 65 + lane];
        }
        #pragma unroll
        for (int j = 0; j < 4; ++j) {
            const float* qrow = q + (rbase + j) * 64 + d0;   // wave-uniform -> s_load
            const float* krow = k + (rbase + j) * 64 + d0;
            #pragma unroll
            for (int d = 0; d < 16; ++d) {
                accq[j] = fmaf(qrow[d], wq[d], accq[j]);
                acck[j] = fmaf(krow[d], wk[d], acck[j]);
            }
        }
    }
    float bh_e = b_h[lane];
    float wo = W_o[lane];
    float bo = b_o[0];
    #pragma unroll
    for (int j = 0; j < 4; ++j) {
        float aq = accq[j];
        float ak = acck[j] + bh_e;
        qp[(rbase + j) * 64 + lane] = aq;
        kpb[(rbase + j) * 64 + lane] = ak;
        float sq = wo * aq, sk = wo * ak;
        #pragma unroll
        for (int off = 32; off > 0; off >>= 1) {
            sq += __shfl_xor(sq, off, 64);
            sk += __shfl_xor(sk, off, 64);
        }
        if (lane == 0) {
            cq6[rbase + j] = 0.6f * sq + bo;
            ck6[rbase + j] = 0.6f * sk;
        }
    }
}

// attn: QBLK=4, grid 2048 (8 blocks/CU queue), 512 thr. Structure as R12:
// e-split halves, packed-fp32 scores, no-max softmax, f16 p broadcasts in D.
__global__ __launch_bounds__(512, 4) void attn_kernel(
    const float* __restrict__ qp, const float* __restrict__ kpb,
    const float* __restrict__ V, const int* __restrict__ mask,
    const float* __restrict__ cq6, const float* __restrict__ ck6,
    const float* __restrict__ w4g,
    float* __restrict__ out)
{
    __shared__ float sc[2048];        // scores [half][row][m] (8 KB); later PV partials
    __shared__ _Float16 pf[1024];     // [row][m] p as f16 (2 KB)
    __shared__ float red_s[8][2];

    int t = threadIdx.x;
    int lane = t & 63;
    int wid = __builtin_amdgcn_readfirstlane(t >> 6);   // 0..7
    int h = wid >> 2;                // 0/1, wave-uniform
    int m = t & 255;
    int bid = blockIdx.x;
    int work = (bid & 7) * 256 + (bid >> 3);   // 2048 = 8*256 bijective
    int bh = work >> 6;
    int nb = work & 63;
    int b = bh >> 3;
    int n0 = nb * QBLK;
    int kvbase = bh * N * 64;

    const float4* kp4 = reinterpret_cast<const float4*>(kpb + kvbase + m * 64 + h * 32);
    float4 c0 = kp4[0], c1 = kp4[1];   // first kv chunk in flight

    // mask rows needed in phase B (rows h*2, h*2+1), as 0/1 floats
    float mf[2];
    #pragma unroll
    for (int i = 0; i < 2; ++i)
        mf[i] = (mask[(b * N + n0 + h * 2 + i) * N + m] != 0) ? 1.0f : 0.0f;

    float ckt = (h == 0) ? ck6[bh * N + m] : 0.f;

    // ---- phase A: packed partial scores for 4 rows over this half's 32 e's ----
    v2f sp2[QBLK];
    const float* cq = cq6 + bh * N + n0;   // uniform
    #pragma unroll
    for (int r = 0; r < QBLK; ++r) {
        float init = (h == 0) ? (cq[r] + ckt) : 0.f;
        sp2[r] = (v2f){init, 0.f};
    }

    const v2f* qr2 = reinterpret_cast<const v2f*>(qp + (bh * N + n0) * 64 + h * 32);  // uniform
    const v2f* w42 = reinterpret_cast<const v2f*>(w4g + h * 32);                      // uniform
    #pragma unroll
    for (int chunk = 0; chunk < 4; ++chunk) {
        float4 pf0, pf1;
        if (chunk < 3) { pf0 = kp4[2 * chunk + 2]; pf1 = kp4[2 * chunk + 3]; }
        v2f kp2[4] = {{c0.x, c0.y}, {c0.z, c0.w}, {c1.x, c1.y}, {c1.z, c1.w}};
        #pragma unroll
        for (int p = 0; p < 4; ++p) {
            v2f w2 = w42[chunk * 4 + p];
            v2f k2 = kp2[p];
            #pragma unroll
            for (int r = 0; r < QBLK; ++r) {
                v2f x = qr2[r * 32 + chunk * 4 + p] + k2;           // v_pk_add_f32
                v2f ax = __builtin_elementwise_max(x, -x);          // v_pk_max_f32
                sp2[r] = __builtin_elementwise_fma(w2, ax, sp2[r]); // v_pk_fma_f32
            }
        }
        c0 = pf0; c1 = pf1;
    }
    #pragma unroll
    for (int r = 0; r < QBLK; ++r)
        sc[h * 1024 + r * 256 + m] = sp2[r].x + sp2[r].y;   // conflict-free

    // V prefetch for phase D group 0 (8 values)
    const float* Vp = V + kvbase + wid * 32 * 64 + lane;
    float vpre[8];
    #pragma unroll
    for (int g = 0; g < 8; ++g) vpre[g] = Vp[g * 64];
    __syncthreads();

    // ---- phase B: rows h*2, h*2+1, this wave's 64-m chunk; no max pass ----
    float p8[2];
    #pragma unroll
    for (int i = 0; i < 2; ++i) {
        int rr = h * 2 + i;
        float s = sc[rr * 256 + m] + sc[1024 + rr * 256 + m];
        float p = __expf(s) * mf[i];
        p8[i] = p;
        float l = p;
        #pragma unroll
        for (int off = 32; off > 0; off >>= 1) l += __shfl_xor(l, off, 64);
        if (lane == 0) red_s[wid][i] = l;
    }
    __syncthreads();

    // ---- phase C: merge 4 m-chunk sums per row; write p_attn + pf (f16) ----
    #pragma unroll
    for (int i = 0; i < 2; ++i) {
        int rr = h * 2 + i;
        float gs = red_s[h*4+0][i] + red_s[h*4+1][i] + red_s[h*4+2][i] + red_s[h*4+3][i];
        float pn = p8[i] * __frcp_rn(gs);
        pf[rr * 256 + m] = (_Float16)pn;                      // ds_write_b16
        out[PATTN_OFF + (bh * N + n0 + rr) * N + m] = pn;     // coalesced fp32
    }
    __syncthreads();

    // ---- phase D: PV. wid = m-chunk of 32, lane = d; f16 p broadcasts ----
    float acc[QBLK] = {};
    {   // group 0 from prefetch
        #pragma unroll
        for (int r = 0; r < QBLK; ++r) {
            h8 ph = *reinterpret_cast<const h8*>(&pf[r * 256 + wid * 32]);
            #pragma unroll
            for (int g = 0; g < 8; ++g)
                acc[r] = fmaf((float)ph[g], vpre[g], acc[r]);   // -> v_fma_mix_f32
        }
    }
    #pragma unroll
    for (int j = 8; j < 32; j += 8) {
        float vv[8];
        #pragma unroll
        for (int g = 0; g < 8; ++g) vv[g] = Vp[(j + g) * 64];
        #pragma unroll
        for (int r = 0; r < QBLK; ++r) {
            h8 ph = *reinterpret_cast<const h8*>(&pf[r * 256 + wid * 32 + j]);
            #pragma unroll
            for (int g = 0; g < 8; ++g)
                acc[r] = fmaf((float)ph[g], vv[g], acc[r]);
        }
    }
    __syncthreads();   // sc score region dead; reuse for PV partials

    #pragma unroll
    for (int r = 0; r < QBLK; ++r)
        sc[wid * 256 + r * 64 + lane] = acc[r];
    __syncthreads();

    // final: threads t<256: row rr = t>>6, d = t&63; sum the 8 m-chunk partials
    if (t < 256) {
        int rr = t >> 6, d = t & 63;
        float o = 0.f;
        #pragma unroll
        for (int mc = 0; mc < 8; ++mc)
            o += sc[mc * 256 + rr * 64 + d];
        out[(bh * N + n0 + rr) * 64 + d] = o;
    }
}

extern "C" void kernel_launch(void* const* d_in, const int* in_sizes, int n_in,
                              void* d_out, int out_size, void* d_ws, size_t ws_size,
                              hipStream_t stream) {
    const float* q    = (const float*)d_in[0];
    const float* k    = (const float*)d_in[1];
    const float* v    = (const float*)d_in[2];
    const int*   mask = (const int*)d_in[3];
    const float* W_h  = (const float*)d_in[4];
    const float* b_h  = (const float*)d_in[5];
    const float* W_o  = (const float*)d_in[6];
    const float* b_o  = (const float*)d_in[7];
    float* out = (float*)d_out;

    float* qp  = (float*)d_ws;
    float* kpb = qp + NROWS * 64;
    float* cq6 = kpb + NROWS * 64;
    float* ck6 = cq6 + NROWS;
    float* w4  = ck6 + NROWS;

    proj_kernel<<<NROWS / 16, 256, 0, stream>>>(q, k, W_h, b_h, W_o, b_o, qp, kpb, cq6, ck6, w4);
    attn_kernel<<<B * H * (N / QBLK), 512, 0, stream>>>(qp, kpb, v, mask, cq6, ck6, w4, out);
}

// Round 14
// 35.118 us; speedup vs baseline: 1.1516x; 1.1516x over previous
//
#include <hip/hip_runtime.h>

typedef float v2f __attribute__((ext_vector_type(2)));
typedef _Float16 h8 __attribute__((ext_vector_type(8)));

constexpr int B = 4, H = 8, N = 256, D = 64;
constexpr int QBLK = 8;
constexpr int PATTN_OFF = B * H * N * D;   // 524288
constexpr int NROWS = B * H * N;           // 8192

// ws layout: qp[NROWS*64] f32 | kpbh[NROWS*64] f16 (in old kpb slot) |
//            cq6[NROWS] | ck6[NROWS] | w4[64]

// proj: R12 structure (grid 512, 4 rows/wave, 2 blocks/CU, LDS-transposed W_h
// stride 65 conflict-free); kpb now stored as f16.
__global__ __launch_bounds__(256, 2) void proj_kernel(
    const float* __restrict__ q, const float* __restrict__ k,
    const float* __restrict__ W_h, const float* __restrict__ b_h,
    const float* __restrict__ W_o, const float* __restrict__ b_o,
    float* __restrict__ qp, _Float16* __restrict__ kpbh,
    float* __restrict__ cq6, float* __restrict__ ck6, float* __restrict__ w4)
{
    __shared__ float WT[128 * 65];
    int t = threadIdx.x;
    int lane = t & 63;
    int wid = __builtin_amdgcn_readfirstlane(t >> 6);
    int bid = blockIdx.x;
    int work = (bid & 7) * 64 + (bid >> 3);   // 512 = 8*64 bijective XCD swizzle

    #pragma unroll
    for (int i = 0; i < 8; ++i) {
        int fidx = (t + i * 256) * 4;
        float4 w = *reinterpret_cast<const float4*>(W_h + fidx);
        int e = fidx >> 7, d = fidx & 127;
        WT[(d + 0) * 65 + e] = w.x;
        WT[(d + 1) * 65 + e] = w.y;
        WT[(d + 2) * 65 + e] = w.z;
        WT[(d + 3) * 65 + e] = w.w;
    }
    if (bid == 0 && t < 64) w4[t] = 0.4f * W_o[t];
    __syncthreads();

    int rbase = work * 16 + wid * 4;   // 4 rows per wave, e = lane
    float accq[4] = {}, acck[4] = {};
    #pragma unroll
    for (int d0 = 0; d0 < 64; d0 += 16) {
        float wq[16], wk[16];
        #pragma unroll
        for (int d = 0; d < 16; ++d) {
            wq[d] = WT[(d0 + d) * 65 + lane];
            wk[d] = WT[(64 + d0 + d) * 65 + lane];
        }
        #pragma unroll
        for (int j = 0; j < 4; ++j) {
            const float* qrow = q + (rbase + j) * 64 + d0;   // wave-uniform -> s_load
            const float* krow = k + (rbase + j) * 64 + d0;
            #pragma unroll
            for (int d = 0; d < 16; ++d) {
                accq[j] = fmaf(qrow[d], wq[d], accq[j]);
                acck[j] = fmaf(krow[d], wk[d], acck[j]);
            }
        }
    }
    float bh_e = b_h[lane];
    float wo = W_o[lane];
    float bo = b_o[0];
    #pragma unroll
    for (int j = 0; j < 4; ++j) {
        float aq = accq[j];
        float ak = acck[j] + bh_e;
        qp[(rbase + j) * 64 + lane] = aq;
        kpbh[(rbase + j) * 64 + lane] = (_Float16)ak;
        float sq = wo * aq, sk = wo * ak;
        #pragma unroll
        for (int off = 32; off > 0; off >>= 1) {
            sq += __shfl_xor(sq, off, 64);
            sk += __shfl_xor(sk, off, 64);
        }
        if (lane == 0) {
            cq6[rbase + j] = 0.6f * sq + bo;
            ck6[rbase + j] = 0.6f * sk;
        }
    }
}

// attn: R12 structure exactly (QBLK=8, grid 1024, 512 thr, e-split halves,
// packed-fp32 scores, no-max softmax, f16 p broadcasts in D); kv now f16
// (4 x h8 loads up front, half the L2 bytes, ~8 fewer live VGPRs).
__global__ __launch_bounds__(512, 2) void attn_kernel(
    const float* __restrict__ qp, const _Float16* __restrict__ kpbh,
    const float* __restrict__ V, const int* __restrict__ mask,
    const float* __restrict__ cq6, const float* __restrict__ ck6,
    const float* __restrict__ w4g,
    float* __restrict__ out)
{
    __shared__ float sc[4096];        // scores [half][row][m]; later PV partials
    __shared__ _Float16 pf[2048];     // [row][m] p as f16 (4 KB)
    __shared__ float red_s[8][4];

    int t = threadIdx.x;
    int lane = t & 63;
    int wid = __builtin_amdgcn_readfirstlane(t >> 6);   // 0..7
    int h = wid >> 2;                // 0/1, wave-uniform
    int m = t & 255;
    int bid = blockIdx.x;
    int work = (bid & 7) * 128 + (bid >> 3);   // 1024 = 8*128 bijective
    int bh = work >> 5;
    int nb = work & 31;
    int b = bh >> 3;
    int n0 = nb * QBLK;
    int kvbase = bh * N * 64;

    // kv: kpbh[m][32h .. 32h+31] as 4 x h8 (64 B contiguous, coalesced)
    const h8* kph = reinterpret_cast<const h8*>(kpbh + kvbase + m * 64 + h * 32);
    h8 kh0 = kph[0], kh1 = kph[1], kh2 = kph[2], kh3 = kph[3];

    float mf[4];
    #pragma unroll
    for (int i = 0; i < 4; ++i)
        mf[i] = (mask[(b * N + n0 + h * 4 + i) * N + m] != 0) ? 1.0f : 0.0f;

    float ckt = (h == 0) ? ck6[bh * N + m] : 0.f;

    // ---- phase A: packed partial scores for 8 rows over this half's 32 e's ----
    v2f sp2[8];
    const float* cq = cq6 + bh * N + n0;   // uniform
    #pragma unroll
    for (int r = 0; r < 8; ++r) {
        float init = (h == 0) ? (cq[r] + ckt) : 0.f;
        sp2[r] = (v2f){init, 0.f};
    }

    const v2f* qr2 = reinterpret_cast<const v2f*>(qp + (bh * N + n0) * 64 + h * 32);  // uniform
    const v2f* w42 = reinterpret_cast<const v2f*>(w4g + h * 32);                      // uniform
    #pragma unroll
    for (int chunk = 0; chunk < 4; ++chunk) {
        h8 kc = (chunk == 0) ? kh0 : (chunk == 1) ? kh1 : (chunk == 2) ? kh2 : kh3;
        #pragma unroll
        for (int p = 0; p < 4; ++p) {
            v2f w2 = w42[chunk * 4 + p];
            v2f k2 = (v2f){(float)kc[2 * p], (float)kc[2 * p + 1]};
            #pragma unroll
            for (int r = 0; r < 8; ++r) {
                v2f x = qr2[r * 32 + chunk * 4 + p] + k2;           // v_pk_add_f32
                v2f ax = __builtin_elementwise_max(x, -x);          // v_pk_max_f32
                sp2[r] = __builtin_elementwise_fma(w2, ax, sp2[r]); // v_pk_fma_f32
            }
        }
    }
    #pragma unroll
    for (int r = 0; r < 8; ++r)
        sc[h * 2048 + r * 256 + m] = sp2[r].x + sp2[r].y;   // conflict-free

    // V prefetch for phase D group 0 (8 values)
    const float* Vp = V + kvbase + wid * 32 * 64 + lane;
    float vpre[8];
    #pragma unroll
    for (int g = 0; g < 8; ++g) vpre[g] = Vp[g * 64];
    __syncthreads();

    // ---- phase B: rows h*4..h*4+3, this wave's 64-m chunk; no max pass ----
    float p8[4];
    #pragma unroll
    for (int i = 0; i < 4; ++i) {
        int rr = h * 4 + i;
        float s = sc[rr * 256 + m] + sc[2048 + rr * 256 + m];
        float p = __expf(s) * mf[i];
        p8[i] = p;
        float l = p;
        #pragma unroll
        for (int off = 32; off > 0; off >>= 1) l += __shfl_xor(l, off, 64);
        if (lane == 0) red_s[wid][i] = l;
    }
    __syncthreads();

    // ---- phase C: merge sums; write p_attn (fp32 global) + pf (f16 LDS) ----
    #pragma unroll
    for (int i = 0; i < 4; ++i) {
        int rr = h * 4 + i;
        float gs = red_s[h*4+0][i] + red_s[h*4+1][i] + red_s[h*4+2][i] + red_s[h*4+3][i];
        float pn = p8[i] * __frcp_rn(gs);
        pf[rr * 256 + m] = (_Float16)pn;                      // ds_write_b16
        out[PATTN_OFF + (bh * N + n0 + rr) * N + m] = pn;     // coalesced fp32
    }
    __syncthreads();

    // ---- phase D: PV. wid = m-chunk of 32, lane = d; f16 p broadcasts ----
    float acc[8] = {};
    {   // group 0 from prefetch
        #pragma unroll
        for (int r = 0; r < 8; ++r) {
            h8 ph = *reinterpret_cast<const h8*>(&pf[r * 256 + wid * 32]);
            #pragma unroll
            for (int g = 0; g < 8; ++g)
                acc[r] = fmaf((float)ph[g], vpre[g], acc[r]);   // -> v_fma_mix_f32
        }
    }
    #pragma unroll
    for (int j = 8; j < 32; j += 8) {
        float vv[8];
        #pragma unroll
        for (int g = 0; g < 8; ++g) vv[g] = Vp[(j + g) * 64];
        #pragma unroll
        for (int r = 0; r < 8; ++r) {
            h8 ph = *reinterpret_cast<const h8*>(&pf[r * 256 + wid * 32 + j]);
            #pragma unroll
            for (int g = 0; g < 8; ++g)
                acc[r] = fmaf((float)ph[g], vv[g], acc[r]);
        }
    }
    __syncthreads();   // sc score region dead; reuse for PV partials

    #pragma unroll
    for (int r = 0; r < 8; ++r)
        sc[wid * 512 + r * 64 + lane] = acc[r];
    __syncthreads();

    // final: wave wid owns row wid, lane = d; sum the 8 m-chunk partials
    float o = 0.f;
    #pragma unroll
    for (int mc = 0; mc < 8; ++mc)
        o += sc[mc * 512 + wid * 64 + lane];
    out[(bh * N + n0 + wid) * 64 + lane] = o;
}

extern "C" void kernel_launch(void* const* d_in, const int* in_sizes, int n_in,
                              void* d_out, int out_size, void* d_ws, size_t ws_size,
                              hipStream_t stream) {
    const float* q    = (const float*)d_in[0];
    const float* k    = (const float*)d_in[1];
    const float* v    = (const float*)d_in[2];
    const int*   mask = (const int*)d_in[3];
    const float* W_h  = (const float*)d_in[4];
    const float* b_h  = (const float*)d_in[5];
    const float* W_o  = (const float*)d_in[6];
    const float* b_o  = (const float*)d_in[7];
    float* out = (float*)d_out;

    float* qp       = (float*)d_ws;
    _Float16* kpbh  = (_Float16*)(qp + NROWS * 64);
    float* cq6      = (float*)(qp + NROWS * 64 + NROWS * 64);  // old kpb slot is f32-sized; f16 uses half
    float* ck6      = cq6 + NROWS;
    float* w4       = ck6 + NROWS;

    proj_kernel<<<NROWS / 16, 256, 0, stream>>>(q, k, W_h, b_h, W_o, b_o, qp, kpbh, cq6, ck6, w4);
    attn_kernel<<<B * H * (N / QBLK), 512, 0, stream>>>(qp, kpbh, v, mask, cq6, ck6, w4, out);
}